// Round 5
// baseline (198.300 us; speedup 1.0000x reference)
//
#include <hip/hip_runtime.h>

#define T_N   131072
#define K_N   64
#define L_C   64
#define F_N   8
#define N_CH  (T_N / L_C)   /* 2048 chunks per direction */
#define EPS_F 1e-10f
#define OBS_MAX ((T_N - 1) * F_N)

#define LOG2E 1.4426950408889634f
#define NL2E  (-0.72134752044448170f)   /* -0.5*log2(e) */
#define LN2   0.6931471805599453f
#define LN2PI 1.8378770664093453f

typedef float v2f __attribute__((ext_vector_type(2)));

/* ---- DPP wave64 sum: VALU-only ---- */
template <int CTRL>
__device__ __forceinline__ float dpp_add(float x) {
  int y = __builtin_amdgcn_update_dpp(0, __float_as_int(x), CTRL, 0xF, 0xF, true);
  return x + __int_as_float(y);
}
__device__ __forceinline__ float wave_sum64(float x) {
  x = dpp_add<0x111>(x);
  x = dpp_add<0x112>(x);
  x = dpp_add<0x114>(x);
  x = dpp_add<0x118>(x);
  x = dpp_add<0x142>(x);
  x = dpp_add<0x143>(x);
  return __int_as_float(__builtin_amdgcn_readlane(__float_as_int(x), 63));
}
/* quad_perm [1,0,3,2]: swap adjacent lanes */
__device__ __forceinline__ float quad_swap1(float x) {
  int y = __builtin_amdgcn_update_dpp(0, __float_as_int(x), 0xB1, 0xF, 0xF, true);
  return __int_as_float(y);
}

#define PKFMA(a, b, c) __builtin_elementwise_fma(a, b, c)

/* emission via packed fp32: exp2(ccst + sum_f x*(x*civ + cmiv)) */
__device__ __forceinline__ float em_pk(const float4& xa, const float4& xb,
                                       const v2f civ2[4], const v2f cmiv2[4],
                                       float ccst) {
  v2f x0 = {xa.x, xa.y}, x1 = {xa.z, xa.w};
  v2f x2 = {xb.x, xb.y}, x3 = {xb.z, xb.w};
  v2f a0 = {ccst, 0.f}, a1 = {0.f, 0.f};
  a0 = PKFMA(x0, PKFMA(x0, civ2[0], cmiv2[0]), a0);
  a1 = PKFMA(x1, PKFMA(x1, civ2[1], cmiv2[1]), a1);
  a0 = PKFMA(x2, PKFMA(x2, civ2[2], cmiv2[2]), a0);
  a1 = PKFMA(x3, PKFMA(x3, civ2[3], cmiv2[3]), a1);
  v2f s = a0 + a1;
  return __builtin_amdgcn_exp2f(s.x + s.y);
}

extern "C" __global__ void __launch_bounds__(64, 2)
hdphmm_fb(const float* __restrict__ obs,
          const float* __restrict__ beta_logits,
          const float* __restrict__ pi_logits,
          const float* __restrict__ means,
          const float* __restrict__ log_vars,
          float* __restrict__ out) {
  const int lane = threadIdx.x;
  const int bid  = blockIdx.x;
  const int j    = lane >> 1;
  const int b    = lane & 1;
  const int kbase = 32 * b;
  __shared__ __align__(16) float bufF[2][K_N];
  __shared__ __align__(16) float bufB[2][K_N];
  __shared__ __align__(16) float sstat[K_N * 2];

  float* alpha   = out;
  float* betaout = out + (size_t)T_N * K_N;

  /* ---- per-lane emission coefficients (lane == state), packed ---- */
  v2f civ2[4], cmiv2[4];
  float ccst;
  {
    const float4* mp = reinterpret_cast<const float4*>(means + lane * F_N);
    const float4* lp = reinterpret_cast<const float4*>(log_vars + lane * F_N);
    float4 m0 = mp[0], m1 = mp[1];
    float4 l0 = lp[0], l1 = lp[1];
    float mu[8] = {m0.x, m0.y, m0.z, m0.w, m1.x, m1.y, m1.z, m1.w};
    float lv[8] = {l0.x, l0.y, l0.z, l0.w, l1.x, l1.y, l1.z, l1.w};
    float cst = F_N * LN2PI;
#pragma unroll
    for (int f = 0; f < 8; ++f) {
      float iv = __builtin_amdgcn_exp2f(-lv[f] * LOG2E);
      cst += lv[f] + mu[f] * mu[f] * iv;
      float cf  = NL2E * iv;
      float cmf = -2.0f * mu[f] * cf;
      civ2[f >> 1][f & 1]  = cf;
      cmiv2[f >> 1][f & 1] = cmf;
    }
    ccst = NL2E * cst;
  }

  /* ---- softmax stats (max, 1/sum) of pi_logits row `lane`; share via LDS ---- */
  {
    const float4* pr4 = reinterpret_cast<const float4*>(pi_logits + lane * K_N);
    float mx = -3.0e38f;
#pragma unroll
    for (int k = 0; k < 16; ++k) {
      float4 r = pr4[k];
      mx = fmaxf(mx, fmaxf(fmaxf(r.x, r.y), fmaxf(r.z, r.w)));
    }
    float s = 0.0f;
#pragma unroll
    for (int k = 0; k < 16; ++k) {
      float4 r = pr4[k];
      s += __builtin_amdgcn_exp2f((r.x - mx) * LOG2E);
      s += __builtin_amdgcn_exp2f((r.y - mx) * LOG2E);
      s += __builtin_amdgcn_exp2f((r.z - mx) * LOG2E);
      s += __builtin_amdgcn_exp2f((r.w - mx) * LOG2E);
    }
    reinterpret_cast<float2*>(sstat)[lane] =
        make_float2(mx, __builtin_amdgcn_rcpf(s));
  }
  __syncthreads();

  const int cb = N_CH - 1 - bid;                       /* bwd chunk index */
  const int wn = (64 * bid < 96) ? 64 * bid : 96;      /* shared warm count */

  /* ---- FWD T fragments: tA/tB[i] = (E[k0][col], E[k0+1][col]) k0=kbase+2i ---- */
  v2f tA[16], tB[16];
#pragma unroll
  for (int i = 0; i < 16; ++i) {
    int k0 = kbase + 2 * i;
    float2 p0 = *reinterpret_cast<const float2*>(pi_logits + k0 * K_N + 2 * j);
    float2 p1 = *reinterpret_cast<const float2*>(pi_logits + (k0 + 1) * K_N + 2 * j);
    float2 s0 = reinterpret_cast<const float2*>(sstat)[k0];
    float2 s1 = reinterpret_cast<const float2*>(sstat)[k0 + 1];
    tA[i] = (v2f){__builtin_amdgcn_exp2f((p0.x - s0.x) * LOG2E) * s0.y,
                  __builtin_amdgcn_exp2f((p1.x - s1.x) * LOG2E) * s1.y};
    tB[i] = (v2f){__builtin_amdgcn_exp2f((p0.y - s0.x) * LOG2E) * s0.y,
                  __builtin_amdgcn_exp2f((p1.y - s1.x) * LOG2E) * s1.y};
  }
  /* ---- BWD row fragments: rA = row 2j, rB = row 2j+1, k-pairs ---- */
  v2f rA[16], rB[16];
  {
    float2 msj  = reinterpret_cast<const float2*>(sstat)[2 * j];
    float2 msj1 = reinterpret_cast<const float2*>(sstat)[2 * j + 1];
    const float4* pr0 = reinterpret_cast<const float4*>(pi_logits + (2 * j) * K_N + kbase);
    const float4* pr1 = reinterpret_cast<const float4*>(pi_logits + (2 * j + 1) * K_N + kbase);
#pragma unroll
    for (int i = 0; i < 8; ++i) {
      float4 q0 = pr0[i], q1 = pr1[i];
      rA[2*i]   = (v2f){__builtin_amdgcn_exp2f((q0.x - msj.x) * LOG2E) * msj.y,
                        __builtin_amdgcn_exp2f((q0.y - msj.x) * LOG2E) * msj.y};
      rA[2*i+1] = (v2f){__builtin_amdgcn_exp2f((q0.z - msj.x) * LOG2E) * msj.y,
                        __builtin_amdgcn_exp2f((q0.w - msj.x) * LOG2E) * msj.y};
      rB[2*i]   = (v2f){__builtin_amdgcn_exp2f((q1.x - msj1.x) * LOG2E) * msj1.y,
                        __builtin_amdgcn_exp2f((q1.y - msj1.x) * LOG2E) * msj1.y};
      rB[2*i+1] = (v2f){__builtin_amdgcn_exp2f((q1.z - msj1.x) * LOG2E) * msj1.y,
                        __builtin_amdgcn_exp2f((q1.w - msj1.x) * LOG2E) * msj1.y};
    }
  }

  /* ---- FWD chain init (chunk bid) ---- */
  float vPrevF, SF;
  int pF = 0, offF, outF;
  float4 xaF, xbF;
  {
    const int out_lo = 64 * bid;
    float v;
    int t_first;
    if (bid <= 1) {
      /* exact stick-breaking init at t=0 */
      float bl = beta_logits[lane];
      float ex = __builtin_amdgcn_exp2f(-bl * LOG2E);
      float bw = __builtin_amdgcn_rcpf(1.0f + ex);
      bufF[1][lane] = 1.0f - bw;
      __syncthreads();
      float pr = 1.0f;
#pragma unroll
      for (int i = 0; i < 64; ++i) {
        float q = bufF[1][i];
        pr = (i < lane) ? pr * q : pr;
      }
      float4 x0 = reinterpret_cast<const float4*>(obs)[0];
      float4 x1 = reinterpret_cast<const float4*>(obs)[1];
      v = bw * pr * em_pk(x0, x1, civ2, cmiv2, ccst);
      t_first = 1;
    } else {
      const int t0 = out_lo - 96;
      const float4* xp = reinterpret_cast<const float4*>(obs + t0 * F_N);
      v = em_pk(xp[0], xp[1], civ2, cmiv2, ccst);     /* flat warm start */
      t_first = t0 + 1;
    }
    bufF[0][lane] = v;
    SF = wave_sum64(v);
    vPrevF = v;
    offF = t_first * F_N;
    const float4* xp = reinterpret_cast<const float4*>(obs + offF);
    xaF = xp[0]; xbF = xp[1];
    outF = out_lo * K_N + lane;
  }

  /* ---- BWD chain init (chunk cb) ---- */
  float uPrev, SB;
  int pB = 0, offB, outB;
  float4 xaB, xbB;
  {
    const int t_hi = cb * L_C + L_C - 1;
    int t_top = t_hi + 96;
    if (t_top > T_N - 1) t_top = T_N - 1;   /* bid<=1: exact bT anchor */
    uPrev = 1.0f;
    SB = 1.0f;                              /* bT enters unnormalized */
    const float4* xp = reinterpret_cast<const float4*>(obs + t_top * F_N);
    bufB[0][lane] = em_pk(xp[0], xp[1], civ2, cmiv2, ccst);
    offB = (t_top - 1) * F_N;
    const float4* xq = reinterpret_cast<const float4*>(obs + offB);
    xaB = xq[0]; xbB = xq[1];
    outB = (t_top - wn) * K_N + lane;       /* == t_hi (generic) / T-1 (bid=0) */
  }

#define STEP(DO_STORE)                                                        \
  {                                                                           \
    /* ---------- forward chain ---------- */                                 \
    int offFn = offF + F_N; offFn = (offFn > OBS_MAX) ? OBS_MAX : offFn;      \
    float4 nxaF = *reinterpret_cast<const float4*>(obs + offFn);              \
    float4 nxbF = *reinterpret_cast<const float4*>(obs + offFn + 4);          \
    const float4* wf = reinterpret_cast<const float4*>(bufF[pF]) + 8 * b;     \
    v2f aA0 = {0.f,0.f}, aA1 = {0.f,0.f}, aB0 = {0.f,0.f}, aB1 = {0.f,0.f};   \
    _Pragma("unroll")                                                         \
    for (int i = 0; i < 8; ++i) {                                             \
      float4 w = wf[i];                                                       \
      v2f wl = {w.x, w.y}, wh = {w.z, w.w};                                   \
      aA0 = PKFMA(wl, tA[2*i],   aA0);                                        \
      aA1 = PKFMA(wh, tA[2*i+1], aA1);                                        \
      aB0 = PKFMA(wl, tB[2*i],   aB0);                                        \
      aB1 = PKFMA(wh, tB[2*i+1], aB1);                                        \
    }                                                                         \
    v2f sAF = aA0 + aA1, sBF = aB0 + aB1;                                     \
    float pAv = sAF.x + sAF.y, pBv = sBF.x + sBF.y;                           \
    float sendF = b ? pAv : pBv, keepF = b ? pBv : pAv;                       \
    float mF = keepF + quad_swap1(sendF);                                     \
    float rF = __builtin_amdgcn_rcpf(SF + EPS_F);                             \
    if (DO_STORE) { alpha[outF] = vPrevF * rF; outF += K_N; }                 \
    float eF = em_pk(xaF, xbF, civ2, cmiv2, ccst);                            \
    float vnF = mF * rF * eF;                                                 \
    pF ^= 1; bufF[pF][lane] = vnF;                                            \
    SF = wave_sum64(vnF);                                                     \
    vPrevF = vnF; xaF = nxaF; xbF = nxbF; offF = offFn;                       \
    /* ---------- backward chain ---------- */                                \
    int offBn = offB - F_N; offBn = (offBn < 0) ? 0 : offBn;                  \
    float4 nxaB = *reinterpret_cast<const float4*>(obs + offBn);              \
    float4 nxbB = *reinterpret_cast<const float4*>(obs + offBn + 4);          \
    const float4* wb = reinterpret_cast<const float4*>(bufB[pB]) + 8 * b;     \
    v2f bA0 = {0.f,0.f}, bA1 = {0.f,0.f}, bB0 = {0.f,0.f}, bB1 = {0.f,0.f};   \
    _Pragma("unroll")                                                         \
    for (int i = 0; i < 8; ++i) {                                             \
      float4 w = wb[i];                                                       \
      v2f wl = {w.x, w.y}, wh = {w.z, w.w};                                   \
      bA0 = PKFMA(wl, rA[2*i],   bA0);                                        \
      bA1 = PKFMA(wh, rA[2*i+1], bA1);                                        \
      bB0 = PKFMA(wl, rB[2*i],   bB0);                                        \
      bB1 = PKFMA(wh, rB[2*i+1], bB1);                                        \
    }                                                                         \
    v2f sAB = bA0 + bA1, sBB = bB0 + bB1;                                     \
    float qAv = sAB.x + sAB.y, qBv = sBB.x + sBB.y;                           \
    float sendB = b ? qAv : qBv, keepB = b ? qBv : qAv;                       \
    float mB = keepB + quad_swap1(sendB);                                     \
    float rB = __builtin_amdgcn_rcpf(SB + EPS_F);                             \
    if (DO_STORE) { betaout[outB] = uPrev * rB; outB -= K_N; }                \
    float u2 = mB * rB;                                                       \
    float eB = em_pk(xaB, xbB, civ2, cmiv2, ccst);                            \
    pB ^= 1; bufB[pB][lane] = u2 * eB;                                        \
    SB = wave_sum64(u2);                                                      \
    uPrev = u2; xaB = nxaB; xbB = nxbB; offB = offBn;                         \
  }

#pragma unroll 1
  for (int it = 0; it < wn; ++it) STEP(0)
#pragma unroll 1
  for (int it = 0; it < L_C - 1; ++it) STEP(1)
#undef STEP

  /* epilogue */
  {
    float rF = __builtin_amdgcn_rcpf(SF + EPS_F);
    alpha[outF] = vPrevF * rF;
    if (bid == N_CH - 1 && lane == 0) {
      float sl = SF * rF + EPS_F;   /* sum(alpha[-1]) + EPS */
      out[(size_t)2 * T_N * K_N] = __builtin_amdgcn_logf(sl) * LN2;
    }
    float rB = __builtin_amdgcn_rcpf(SB + EPS_F);
    betaout[outB] = uPrev * rB;
  }
}

extern "C" void kernel_launch(void* const* d_in, const int* in_sizes, int n_in,
                              void* d_out, int out_size, void* d_ws, size_t ws_size,
                              hipStream_t stream) {
  (void)in_sizes; (void)n_in; (void)out_size; (void)d_ws; (void)ws_size;
  const float* obs  = (const float*)d_in[0];
  const float* bl   = (const float*)d_in[1];
  const float* pi   = (const float*)d_in[2];
  const float* mns  = (const float*)d_in[3];
  const float* lvs  = (const float*)d_in[4];
  hipLaunchKernelGGL(hdphmm_fb, dim3(N_CH), dim3(64), 0, stream,
                     obs, bl, pi, mns, lvs, (float*)d_out);
}

// Round 6
// 179.423 us; speedup vs baseline: 1.1052x; 1.1052x over previous
//
#include <hip/hip_runtime.h>

#define T_N   131072
#define K_N   64
#define L_C   128
#define F_N   8
#define N_CH  (T_N / L_C)   /* 1024 chunks per direction */
#define WARM  96
#define EPS_F 1e-10f
#define OBS_MAX ((T_N - 1) * F_N)

#define LOG2E 1.4426950408889634f
#define NL2E  (-0.72134752044448170f)   /* -0.5*log2(e) */
#define LN2   0.6931471805599453f
#define LN2PI 1.8378770664093453f

typedef float v2f __attribute__((ext_vector_type(2)));

__device__ __forceinline__ float dpp_f(float x, const int ctrl) {
  /* cannot template on ctrl through two call sites with same codegen; use macro below */
  return x;
}
#define DPPI(SRC, CTRL) __builtin_amdgcn_update_dpp(0, (SRC), (CTRL), 0xF, 0xF, true)
#define DPPF(SRC, CTRL) __int_as_float(DPPI(__float_as_int(SRC), (CTRL)))

/* ---- DPP wave64 sum: VALU-only ---- */
template <int CTRL>
__device__ __forceinline__ float dpp_add(float x) {
  int y = __builtin_amdgcn_update_dpp(0, __float_as_int(x), CTRL, 0xF, 0xF, true);
  return x + __int_as_float(y);
}
__device__ __forceinline__ float wave_sum64(float x) {
  x = dpp_add<0x111>(x);
  x = dpp_add<0x112>(x);
  x = dpp_add<0x114>(x);
  x = dpp_add<0x118>(x);
  x = dpp_add<0x142>(x);
  x = dpp_add<0x143>(x);
  return __int_as_float(__builtin_amdgcn_readlane(__float_as_int(x), 63));
}

#define PKFMA(a, b, c) __builtin_elementwise_fma(a, b, c)

/* emission: exp2(ccst + sum_f x*(x*civ + cmiv)); coeffs pre-scaled by -0.5*log2e */
__device__ __forceinline__ float em_pk(const float4& xa, const float4& xb,
                                       const v2f civ2[4], const v2f cmiv2[4],
                                       float ccst) {
  v2f x0 = {xa.x, xa.y}, x1 = {xa.z, xa.w};
  v2f x2 = {xb.x, xb.y}, x3 = {xb.z, xb.w};
  v2f a0 = {ccst, 0.f}, a1 = {0.f, 0.f};
  a0 = PKFMA(x0, PKFMA(x0, civ2[0], cmiv2[0]), a0);
  a1 = PKFMA(x1, PKFMA(x1, civ2[1], cmiv2[1]), a1);
  a0 = PKFMA(x2, PKFMA(x2, civ2[2], cmiv2[2]), a0);
  a1 = PKFMA(x3, PKFMA(x3, civ2[3], cmiv2[3]), a1);
  v2f s = a0 + a1;
  return __builtin_amdgcn_exp2f(s.x + s.y);
}

/* 64x64 matvec, state distributed (lane l holds VV = v[l]):
   gather 16 row-local values via DPP doubling; 4 column-partials per lane
   (cols {h, h+16, h+32, h+48}); butterfly-reduce over q = lane>>4 via
   swizzle(xor16) + bpermute(xor32). Result: MOUT = m[lane]. */
#define MATVEC(VV, MOUT)                                                      \
  {                                                                           \
    float Gr[16];                                                             \
    Gr[0] = (VV);                                                             \
    Gr[1] = DPPF(Gr[0], 0xB1);                        /* quad xor1 */         \
    Gr[2] = DPPF(Gr[0], 0x4E);                        /* quad xor2 */         \
    Gr[3] = DPPF(Gr[1], 0x4E);                                                \
    _Pragma("unroll")                                                         \
    for (int rr = 0; rr < 4; ++rr) Gr[4 + rr] = DPPF(Gr[rr], 0x124);          \
    _Pragma("unroll")                                                         \
    for (int rr = 0; rr < 8; ++rr) Gr[8 + rr] = DPPF(Gr[rr], 0x128);          \
    v2f aE0 = {0.f,0.f}, aE1 = {0.f,0.f}, aO0 = {0.f,0.f}, aO1 = {0.f,0.f};   \
    _Pragma("unroll")                                                         \
    for (int rr = 0; rr < 8; ++rr) {                                          \
      v2f gg = {Gr[rr], Gr[rr]};                                              \
      aE0 = PKFMA(gg, TcE[rr], aE0);                                          \
      aO0 = PKFMA(gg, TcO[rr], aO0);                                          \
    }                                                                         \
    _Pragma("unroll")                                                         \
    for (int rr = 8; rr < 16; ++rr) {                                         \
      v2f gg = {Gr[rr], Gr[rr]};                                              \
      aE1 = PKFMA(gg, TcE[rr], aE1);                                          \
      aO1 = PKFMA(gg, TcO[rr], aO1);                                          \
    }                                                                         \
    v2f accE = aE0 + aE1, accO = aO0 + aO1;   /* E: m=0,2  O: m=1,3 */        \
    float kx = qb0 ? accO.x : accE.x, ky = qb0 ? accO.y : accE.y;             \
    float sx = qb0 ? accE.x : accO.x, sy = qb0 ? accE.y : accO.y;             \
    float rx = __int_as_float(                                                \
        __builtin_amdgcn_ds_swizzle(__float_as_int(sx), 0x401F));             \
    float ry = __int_as_float(                                                \
        __builtin_amdgcn_ds_swizzle(__float_as_int(sy), 0x401F));             \
    float c0 = kx + rx, c1 = ky + ry;         /* m=(q&1), m=2+(q&1) */        \
    float keep2 = qb1 ? c1 : c0;                                              \
    float send2 = qb1 ? c0 : c1;                                              \
    float got = __int_as_float(                                               \
        __builtin_amdgcn_ds_bpermute(bpaddr, __float_as_int(send2)));         \
    MOUT = keep2 + got;                       /* column h+16q == lane */      \
  }

extern "C" __global__ void __launch_bounds__(64, 2)
hdphmm_fb(const float* __restrict__ obs,
          const float* __restrict__ beta_logits,
          const float* __restrict__ pi_logits,
          const float* __restrict__ means,
          const float* __restrict__ log_vars,
          float* __restrict__ out) {
  const int lane = threadIdx.x;
  const int bid  = blockIdx.x;
  const int h    = lane & 15;
  const int q    = lane >> 4;
  const bool qb0 = (q & 1);
  const bool qb1 = (q >> 1);
  const int bpaddr = (lane ^ 32) << 2;
  __shared__ __align__(8) float2 sstat[K_N];
  __shared__ float sb[K_N];

  float* alpha   = out;
  float* betaout = out + (size_t)T_N * K_N;

  /* ---- per-lane emission coefficients (lane == state), packed ---- */
  v2f civ2[4], cmiv2[4];
  float ccst;
  {
    const float4* mp = reinterpret_cast<const float4*>(means + lane * F_N);
    const float4* lp = reinterpret_cast<const float4*>(log_vars + lane * F_N);
    float4 m0 = mp[0], m1 = mp[1];
    float4 l0 = lp[0], l1 = lp[1];
    float mu[8] = {m0.x, m0.y, m0.z, m0.w, m1.x, m1.y, m1.z, m1.w};
    float lv[8] = {l0.x, l0.y, l0.z, l0.w, l1.x, l1.y, l1.z, l1.w};
    float cst = F_N * LN2PI;
#pragma unroll
    for (int f = 0; f < 8; ++f) {
      float iv = __builtin_amdgcn_exp2f(-lv[f] * LOG2E);
      cst += lv[f] + mu[f] * mu[f] * iv;
      float cf  = NL2E * iv;
      civ2[f >> 1][f & 1]  = cf;
      cmiv2[f >> 1][f & 1] = -2.0f * mu[f] * cf;
    }
    ccst = NL2E * cst;
  }

  /* ---- softmax stats (max, 1/sum) of pi_logits row `lane` -> LDS ---- */
  {
    const float4* pr4 = reinterpret_cast<const float4*>(pi_logits + lane * K_N);
    float mx = -3.0e38f;
#pragma unroll
    for (int k = 0; k < 16; ++k) {
      float4 r = pr4[k];
      mx = fmaxf(mx, fmaxf(fmaxf(r.x, r.y), fmaxf(r.z, r.w)));
    }
    float s = 0.0f;
#pragma unroll
    for (int k = 0; k < 16; ++k) {
      float4 r = pr4[k];
      s += __builtin_amdgcn_exp2f((r.x - mx) * LOG2E);
      s += __builtin_amdgcn_exp2f((r.y - mx) * LOG2E);
      s += __builtin_amdgcn_exp2f((r.z - mx) * LOG2E);
      s += __builtin_amdgcn_exp2f((r.w - mx) * LOG2E);
    }
    sstat[lane] = make_float2(mx, __builtin_amdgcn_rcpf(s));
  }
  __syncthreads();

  /* ---- gather k-indices BY CONSTRUCTION: same DPP chain on lane id ---- */
  int ki[16];
  ki[0] = lane;
  ki[1] = DPPI(ki[0], 0xB1);
  ki[2] = DPPI(ki[0], 0x4E);
  ki[3] = DPPI(ki[1], 0x4E);
#pragma unroll
  for (int rr = 0; rr < 4; ++rr) ki[4 + rr] = DPPI(ki[rr], 0x124);
#pragma unroll
  for (int rr = 0; rr < 8; ++rr) ki[8 + rr] = DPPI(ki[rr], 0x128);

  if (bid < N_CH) {
    /* ================= FORWARD chunk =================
       m[c] = sum_k w[k]*trans[k][c].  TcE[r] = {E[k][h], E[k][h+32]},
       TcO[r] = {E[k][h+16], E[k][h+48]}, k = ki[r]. */
    v2f TcE[16], TcO[16];
#pragma unroll
    for (int rr = 0; rr < 16; ++rr) {
      int k = ki[rr];
      float2 st = sstat[k];
      const float* pk = pi_logits + k * K_N;
      float e0 = __builtin_amdgcn_exp2f((pk[h]      - st.x) * LOG2E) * st.y;
      float e1 = __builtin_amdgcn_exp2f((pk[h + 16] - st.x) * LOG2E) * st.y;
      float e2 = __builtin_amdgcn_exp2f((pk[h + 32] - st.x) * LOG2E) * st.y;
      float e3 = __builtin_amdgcn_exp2f((pk[h + 48] - st.x) * LOG2E) * st.y;
      TcE[rr] = (v2f){e0, e2};
      TcO[rr] = (v2f){e1, e3};
    }

    const int out_lo = bid * L_C;
    float v;
    int t_first;
    if (bid == 0) {
      /* exact stick-breaking init */
      float bl = beta_logits[lane];
      float ex = __builtin_amdgcn_exp2f(-bl * LOG2E);
      float bw = __builtin_amdgcn_rcpf(1.0f + ex);
      sb[lane] = 1.0f - bw;
      __syncthreads();
      float pr = 1.0f;
#pragma unroll
      for (int i = 0; i < 64; ++i) {
        float qv = sb[i];
        pr = (i < lane) ? pr * qv : pr;
      }
      float4 x0 = reinterpret_cast<const float4*>(obs)[0];
      float4 x1 = reinterpret_cast<const float4*>(obs)[1];
      v = bw * pr * em_pk(x0, x1, civ2, cmiv2, ccst);
      t_first = 1;
    } else {
      const int t0 = out_lo - WARM;
      const float4* xp = reinterpret_cast<const float4*>(obs + t0 * F_N);
      v = em_pk(xp[0], xp[1], civ2, cmiv2, ccst);   /* flat warm start */
      t_first = t0 + 1;
    }
    float S = wave_sum64(v);
    int obs_off = t_first * F_N;
    float4 xa, xb;
    {
      const float4* xp = reinterpret_cast<const float4*>(obs + obs_off);
      xa = xp[0]; xb = xp[1];
    }
    int out_off = out_lo * K_N + lane;

#define FWD_STEP(DO_STORE)                                                    \
  {                                                                           \
    int offn = obs_off + F_N; offn = (offn > OBS_MAX) ? OBS_MAX : offn;       \
    float4 nxa = *reinterpret_cast<const float4*>(obs + offn);                \
    float4 nxb = *reinterpret_cast<const float4*>(obs + offn + 4);            \
    float m;                                                                  \
    MATVEC(v, m)                                                              \
    float r = __builtin_amdgcn_rcpf(S + EPS_F);                               \
    if (DO_STORE) { alpha[out_off] = v * r; out_off += K_N; }                 \
    float e = em_pk(xa, xb, civ2, cmiv2, ccst);                               \
    float vn = m * r * e;                                                     \
    S = wave_sum64(vn);                                                       \
    v = vn; xa = nxa; xb = nxb; obs_off = offn;                               \
  }

    const int wn = (bid == 0) ? 0 : WARM;
#pragma unroll 1
    for (int it = 0; it < wn; ++it) FWD_STEP(0)
#pragma unroll 1
    for (int it = 0; it < L_C - 1; ++it) FWD_STEP(1)
#undef FWD_STEP
    float r = __builtin_amdgcn_rcpf(S + EPS_F);
    alpha[out_off] = v * r;
    if (bid == N_CH - 1 && lane == 0) {
      float sl = S * r + EPS_F;
      out[(size_t)2 * T_N * K_N] = __builtin_amdgcn_logf(sl) * LN2;
    }
  } else {
    /* ================= BACKWARD chunk =================
       m[i] = sum_k trans[i][k]*w[k].  TcE[r] = {E[h][k], E[h+32][k]},
       TcO[r] = {E[h+16][k], E[h+48][k]}, k = ki[r]. */
    v2f TcE[16], TcO[16];
    {
      float2 s0 = sstat[h], s1 = sstat[h + 16];
      float2 s2 = sstat[h + 32], s3 = sstat[h + 48];
#pragma unroll
      for (int rr = 0; rr < 16; ++rr) {
        int k = ki[rr];
        float p0 = pi_logits[h * K_N + k];
        float p1 = pi_logits[(h + 16) * K_N + k];
        float p2 = pi_logits[(h + 32) * K_N + k];
        float p3 = pi_logits[(h + 48) * K_N + k];
        TcE[rr] = (v2f){__builtin_amdgcn_exp2f((p0 - s0.x) * LOG2E) * s0.y,
                        __builtin_amdgcn_exp2f((p2 - s2.x) * LOG2E) * s2.y};
        TcO[rr] = (v2f){__builtin_amdgcn_exp2f((p1 - s1.x) * LOG2E) * s1.y,
                        __builtin_amdgcn_exp2f((p3 - s3.x) * LOG2E) * s3.y};
      }
    }
    const int cb   = bid - N_CH;
    const int t_lo = cb * L_C;
    const int t_hi = t_lo + L_C - 1;
    int t_top = t_hi + WARM;
    if (t_top > T_N - 1) t_top = T_N - 1;        /* clamp => exact bT anchor */
    const int s_top = (cb == N_CH - 1) ? T_N - 2 : t_hi;

    float u = 1.0f, S = 1.0f;     /* bT enters UNNORMALIZED: r ~= 1 first */
    float w;
    {
      const float4* xp = reinterpret_cast<const float4*>(obs + t_top * F_N);
      w = em_pk(xp[0], xp[1], civ2, cmiv2, ccst);   /* u(=1)*em[t_top] */
    }
    if (cb == N_CH - 1)
      betaout[(size_t)(T_N - 1) * K_N + lane] = 1.0f;
    int obs_off = (t_top - 1) * F_N;
    float4 xa, xb;
    {
      const float4* xp = reinterpret_cast<const float4*>(obs + obs_off);
      xa = xp[0]; xb = xp[1];
    }
    int out_off = s_top * K_N + lane;

#define BWD_STEP(DO_STORE)                                                    \
  {                                                                           \
    int offn = obs_off - F_N; offn = (offn < 0) ? 0 : offn;                   \
    float4 nxa = *reinterpret_cast<const float4*>(obs + offn);                \
    float4 nxb = *reinterpret_cast<const float4*>(obs + offn + 4);            \
    float m;                                                                  \
    MATVEC(w, m)                                                              \
    float r = __builtin_amdgcn_rcpf(S + EPS_F);                               \
    if (DO_STORE) { betaout[out_off] = u * r; out_off -= K_N; }               \
    float u2 = m * r;                                                         \
    float e = em_pk(xa, xb, civ2, cmiv2, ccst);                               \
    w = u2 * e;                                                               \
    S = wave_sum64(u2);                                                       \
    u = u2; xa = nxa; xb = nxb; obs_off = offn;                               \
  }

    const int warm_n  = t_top - s_top;
    const int store_n = s_top - t_lo;
#pragma unroll 1
    for (int it = 0; it < warm_n; ++it) BWD_STEP(0)
#pragma unroll 1
    for (int it = 0; it < store_n; ++it) BWD_STEP(1)
#undef BWD_STEP
    betaout[t_lo * K_N + lane] = u * __builtin_amdgcn_rcpf(S + EPS_F);
  }
}

extern "C" void kernel_launch(void* const* d_in, const int* in_sizes, int n_in,
                              void* d_out, int out_size, void* d_ws, size_t ws_size,
                              hipStream_t stream) {
  (void)in_sizes; (void)n_in; (void)out_size; (void)d_ws; (void)ws_size;
  const float* obs  = (const float*)d_in[0];
  const float* bl   = (const float*)d_in[1];
  const float* pi   = (const float*)d_in[2];
  const float* mns  = (const float*)d_in[3];
  const float* lvs  = (const float*)d_in[4];
  hipLaunchKernelGGL(hdphmm_fb, dim3(2 * N_CH), dim3(64), 0, stream,
                     obs, bl, pi, mns, lvs, (float*)d_out);
}